// Round 1
// baseline (226.371 us; speedup 1.0000x reference)
//
#include <hip/hip_runtime.h>

#define NGRAPHS 256
#define SMAX 4096   // max nodes/graph handled in LDS (actual ~450); global fallback otherwise

// K1: per-node dot products p = x.w_rel, r = x.w_root; zero aggdot/starts/ends.
// One wave (64 lanes) per row: lane = feature, coalesced 256B row reads.
__global__ __launch_bounds__(256) void k1_dots(
    const float* __restrict__ x,
    const float* __restrict__ w_rel,
    const float* __restrict__ w_root,
    float* __restrict__ p, float* __restrict__ r, float* __restrict__ aggdot,
    int* __restrict__ starts, int* __restrict__ ends, int N)
{
    int tid = threadIdx.x;
    if (blockIdx.x == 0) { starts[tid] = 0; ends[tid] = 0; }  // tid in [0,256) == NGRAPHS
    int lane = tid & 63;
    int row  = blockIdx.x * 4 + (tid >> 6);
    if (row >= N) return;
    float v = x[(size_t)row * 64 + lane];
    float a = v * w_rel[lane];
    float c = v * w_root[lane];
    #pragma unroll
    for (int off = 32; off > 0; off >>= 1) {
        a += __shfl_down(a, off, 64);
        c += __shfl_down(c, off, 64);
    }
    if (lane == 0) { p[row] = a; r[row] = c; aggdot[row] = 0.0f; }
}

// K2: edge scatter of scalar dots (linearity: (sum x_j).w = sum (x_j.w)),
// plus graph start/end boundary detection on the sorted batch array.
__global__ __launch_bounds__(256) void k2_scatter(
    const int* __restrict__ ei,      // [2, E]: src row then dst row
    const int* __restrict__ batch,
    const float* __restrict__ p,
    float* aggdot,
    int* __restrict__ starts, int* __restrict__ ends,
    int E, int N)
{
    int id = blockIdx.x * 256 + threadIdx.x;
    if (id < E) {
        int s = ei[id];
        int d = ei[E + id];
        atomicAdd(&aggdot[d], p[s]);
    } else {
        int i = id - E;
        if (i < N) {
            int b = batch[i];
            if (i == 0     || batch[i - 1] != b) starts[b] = i;
            if (i == N - 1 || batch[i + 1] != b) ends[b]   = i + 1;
        }
    }
}

// K4: one block per graph. Phase 1: score = tanh(aggdot + b + r) into LDS.
// Phase 2: O(n^2) stable rank (matches lexsort tie-break: score desc, index asc).
// Phase 3: weighted pool of kept rows, divide by kept count.
__global__ __launch_bounds__(256) void k4_topk_pool(
    const float* __restrict__ x,
    const float* aggdot,             // no restrict: aliased with wglob in fallback
    const float* __restrict__ r,
    const float* __restrict__ brel,
    const int* __restrict__ starts,
    const int* __restrict__ ends,
    float* scoreg,                   // fallback scratch (aliases p; p is dead here)
    float* wglob,                    // fallback scratch (aliases aggdot; disjoint phases)
    float* __restrict__ out)
{
    __shared__ float s[SMAX];
    __shared__ float w[SMAX];
    __shared__ float accs[4][64];
    __shared__ int s_cnt;

    int g   = blockIdx.x;
    int tid = threadIdx.x;
    int start = starts[g];
    int n     = ends[g] - start;
    int k     = (n + 1) >> 1;        // ceil(0.5 * n)
    if (tid == 0) s_cnt = 0;
    float b = brel[0];
    bool use_lds = (n <= SMAX);

    if (use_lds) {
        for (int i = tid; i < n; i += 256)
            s[i] = tanhf(aggdot[start + i] + b + r[start + i]);
        __syncthreads();
        int lc = 0;
        for (int i = tid; i < n; i += 256) {
            float si = s[i];
            int rank = 0;
            for (int j = 0; j < n; ++j) {
                float sj = s[j];                 // uniform j: LDS broadcast, no conflicts
                rank += (sj > si) || (sj == si && j < i);
            }
            bool kp = rank < k;
            lc += kp;
            w[i] = kp ? si : 0.0f;
        }
        atomicAdd(&s_cnt, lc);
        __syncthreads();
    } else {
        for (int i = tid; i < n; i += 256)
            scoreg[start + i] = tanhf(aggdot[start + i] + b + r[start + i]);
        __syncthreads();
        int lc = 0;
        for (int i = tid; i < n; i += 256) {
            float si = scoreg[start + i];
            int rank = 0;
            for (int j = 0; j < n; ++j) {
                float sj = scoreg[start + j];
                rank += (sj > si) || (sj == si && j < i);
            }
            bool kp = rank < k;
            lc += kp;
            wglob[start + i] = kp ? si : 0.0f;
        }
        atomicAdd(&s_cnt, lc);
        __syncthreads();
    }

    // Phase 3: pooling. wave w handles rows i = w, w+4, ...; lane = feature.
    int lane_d = tid & 63;
    int grp    = tid >> 6;
    float acc = 0.0f;
    if (use_lds) {
        for (int i = grp; i < n; i += 4) {
            float wv = w[i];                     // wave-uniform -> uniform branch
            if (wv != 0.0f)
                acc += x[(size_t)(start + i) * 64 + lane_d] * wv;
        }
    } else {
        for (int i = grp; i < n; i += 4) {
            float wv = wglob[start + i];
            if (wv != 0.0f)
                acc += x[(size_t)(start + i) * 64 + lane_d] * wv;
        }
    }
    accs[grp][lane_d] = acc;
    __syncthreads();
    if (tid < 64) {
        float sum = accs[0][tid] + accs[1][tid] + accs[2][tid] + accs[3][tid];
        out[(size_t)g * 64 + tid] = sum / fmaxf((float)s_cnt, 1.0f);
    }
}

extern "C" void kernel_launch(void* const* d_in, const int* in_sizes, int n_in,
                              void* d_out, int out_size, void* d_ws, size_t ws_size,
                              hipStream_t stream) {
    const float* x      = (const float*)d_in[0];
    const int*   ei     = (const int*)  d_in[1];
    const int*   batch  = (const int*)  d_in[2];
    const float* w_rel  = (const float*)d_in[3];
    const float* b_rel  = (const float*)d_in[4];
    const float* w_root = (const float*)d_in[5];
    float* out = (float*)d_out;

    int N = in_sizes[2];
    int E = in_sizes[1] / 2;

    // Workspace: p[N], r[N], aggdot[N], starts[256], ends[256]  (~1.2 MB)
    float* ws     = (float*)d_ws;
    float* p      = ws;
    float* r      = ws + (size_t)N;
    float* aggdot = ws + 2 * (size_t)N;
    int*   starts = (int*)(ws + 3 * (size_t)N);
    int*   ends   = starts + NGRAPHS;

    k1_dots<<<(N + 3) / 4, 256, 0, stream>>>(x, w_rel, w_root, p, r, aggdot, starts, ends, N);
    int total = E + N;
    k2_scatter<<<(total + 255) / 256, 256, 0, stream>>>(ei, batch, p, aggdot, starts, ends, E, N);
    // scoreg aliases p (dead), wglob aliases aggdot (disjoint phases) — fallback-only
    k4_topk_pool<<<NGRAPHS, 256, 0, stream>>>(x, aggdot, r, b_rel, starts, ends, p, aggdot, out);
}

// Round 2
// 197.253 us; speedup vs baseline: 1.1476x; 1.1476x over previous
//
#include <hip/hip_runtime.h>

#define NGRAPHS 256
#define SMAX 4096   // max nodes/graph handled in LDS (actual ~450); global fallback otherwise

// K1: per-node dot products p = x.w_rel, r = x.w_root; zero aggdot/starts/ends.
// One wave (64 lanes) per row: lane = feature, coalesced 256B row reads.
__global__ __launch_bounds__(256) void k1_dots(
    const float* __restrict__ x,
    const float* __restrict__ w_rel,
    const float* __restrict__ w_root,
    float* __restrict__ p, float* __restrict__ r, float* __restrict__ aggdot,
    int* __restrict__ starts, int* __restrict__ ends, int N)
{
    int tid = threadIdx.x;
    if (blockIdx.x == 0) { starts[tid] = 0; ends[tid] = 0; }  // tid in [0,256) == NGRAPHS
    int lane = tid & 63;
    int row  = blockIdx.x * 4 + (tid >> 6);
    if (row >= N) return;
    float v = x[(size_t)row * 64 + lane];
    float a = v * w_rel[lane];
    float c = v * w_root[lane];
    #pragma unroll
    for (int off = 32; off > 0; off >>= 1) {
        a += __shfl_down(a, off, 64);
        c += __shfl_down(c, off, 64);
    }
    if (lane == 0) { p[row] = a; r[row] = c; aggdot[row] = 0.0f; }
}

// K2: edge scatter of scalar dots (linearity: (sum x_j).w = sum (x_j.w)),
// plus graph start/end boundary detection on the sorted batch array.
// unsafeAtomicAdd -> HW global_atomic_add_f32 (no CAS loop).
__global__ __launch_bounds__(256) void k2_scatter(
    const int* __restrict__ ei,      // [2, E]: src row then dst row
    const int* __restrict__ batch,
    const float* __restrict__ p,
    float* aggdot,
    int* __restrict__ starts, int* __restrict__ ends,
    int E, int N)
{
    int id = blockIdx.x * 256 + threadIdx.x;
    if (id < E) {
        int s = ei[id];
        int d = ei[E + id];
        unsafeAtomicAdd(&aggdot[d], p[s]);
    } else {
        int i = id - E;
        if (i < N) {
            int b = batch[i];
            if (i == 0     || batch[i - 1] != b) starts[b] = i;
            if (i == N - 1 || batch[i + 1] != b) ends[b]   = i + 1;
        }
    }
}

// K4: one block per graph (block = 512 = 8 waves).
// Phase 1: score = tanh(aggdot + b + r) into LDS.
// Phase 2: O(n^2) stable rank (matches lexsort tie-break: score desc, index asc).
// Phase 3: branchless float4 weighted pool; rows padded to x32 with zero weights.
__global__ __launch_bounds__(512) void k4_topk_pool(
    const float* __restrict__ x,
    const float* aggdot,             // no restrict: aliased with wglob in fallback
    const float* __restrict__ r,
    const float* __restrict__ brel,
    const int* __restrict__ starts,
    const int* __restrict__ ends,
    float* scoreg,                   // fallback scratch (aliases p; p is dead here)
    float* wglob,                    // fallback scratch (aliases aggdot; disjoint phases)
    float* __restrict__ out, int N)
{
    __shared__ float s[SMAX];
    __shared__ float w[SMAX + 32];
    __shared__ float accs[8][64][4];
    __shared__ int s_cnt;

    int g   = blockIdx.x;
    int tid = threadIdx.x;
    int start = starts[g];
    int n     = ends[g] - start;
    int k     = (n + 1) >> 1;        // ceil(0.5 * n)
    if (tid == 0) s_cnt = 0;
    float b = brel[0];
    bool use_lds = (n <= SMAX);

    if (use_lds) {
        for (int i = tid; i < n; i += 512)
            s[i] = tanhf(aggdot[start + i] + b + r[start + i]);
        __syncthreads();
        int lc = 0;
        for (int i = tid; i < n; i += 512) {
            float si = s[i];
            int rank = 0;
            for (int j = 0; j < n; ++j) {
                float sj = s[j];                 // uniform j: LDS broadcast, no conflicts
                rank += (sj > si) || (sj == si && j < i);
            }
            bool kp = rank < k;
            lc += kp;
            w[i] = kp ? si : 0.0f;
        }
        if (lc) atomicAdd(&s_cnt, lc);
        // zero-pad weights to the next multiple of 32 (branchless phase 3)
        int n32 = (n + 31) & ~31;
        for (int i = n + tid; i < n32; i += 512) w[i] = 0.0f;
        __syncthreads();

        // Phase 3: wave wg covers rows {wg*4 + 32t + rgrp}; lane = rgrp*16 + fq.
        // Each wave-load = 64 lanes x 16 B = 1 KB contiguous (4 rows of 256 B).
        int wg   = tid >> 6;
        int lane = tid & 63;
        int rgrp = lane >> 4;
        int fq   = lane & 15;
        float a0 = 0.0f, a1 = 0.0f, a2 = 0.0f, a3 = 0.0f;
        #pragma unroll 2
        for (int base = wg * 4; base < n32; base += 32) {
            float wv = w[base + rgrp];
            int row = start + base + rgrp;
            if (row > N - 1) row = N - 1;        // pad rows read safely, weight=0
            const float* xp = x + (size_t)row * 64 + fq * 4;
            float4 v = *(const float4*)xp;
            a0 += v.x * wv; a1 += v.y * wv; a2 += v.z * wv; a3 += v.w * wv;
        }
        accs[wg][lane][0] = a0; accs[wg][lane][1] = a1;
        accs[wg][lane][2] = a2; accs[wg][lane][3] = a3;
        __syncthreads();
        if (tid < 64) {
            int f = tid;
            float sum = 0.0f;
            #pragma unroll
            for (int gg = 0; gg < 8; ++gg)
                #pragma unroll
                for (int rg = 0; rg < 4; ++rg)
                    sum += accs[gg][rg * 16 + (f >> 2)][f & 3];
            out[(size_t)g * 64 + f] = sum / fmaxf((float)s_cnt, 1.0f);
        }
    } else {
        // global fallback (n > SMAX): rare-path, scalar
        for (int i = tid; i < n; i += 512)
            scoreg[start + i] = tanhf(aggdot[start + i] + b + r[start + i]);
        __syncthreads();
        int lc = 0;
        for (int i = tid; i < n; i += 512) {
            float si = scoreg[start + i];
            int rank = 0;
            for (int j = 0; j < n; ++j) {
                float sj = scoreg[start + j];
                rank += (sj > si) || (sj == si && j < i);
            }
            bool kp = rank < k;
            lc += kp;
            wglob[start + i] = kp ? si : 0.0f;
        }
        if (lc) atomicAdd(&s_cnt, lc);
        __syncthreads();
        int wg   = tid >> 6;
        int lane = tid & 63;
        float acc = 0.0f;
        for (int i = wg; i < n; i += 8) {
            float wv = wglob[start + i];
            acc += x[(size_t)(start + i) * 64 + lane] * wv;
        }
        accs[wg][lane][0] = acc;
        __syncthreads();
        if (tid < 64) {
            float sum = 0.0f;
            #pragma unroll
            for (int gg = 0; gg < 8; ++gg) sum += accs[gg][tid][0];
            out[(size_t)g * 64 + tid] = sum / fmaxf((float)s_cnt, 1.0f);
        }
    }
}

extern "C" void kernel_launch(void* const* d_in, const int* in_sizes, int n_in,
                              void* d_out, int out_size, void* d_ws, size_t ws_size,
                              hipStream_t stream) {
    const float* x      = (const float*)d_in[0];
    const int*   ei     = (const int*)  d_in[1];
    const int*   batch  = (const int*)  d_in[2];
    const float* w_rel  = (const float*)d_in[3];
    const float* b_rel  = (const float*)d_in[4];
    const float* w_root = (const float*)d_in[5];
    float* out = (float*)d_out;

    int N = in_sizes[2];
    int E = in_sizes[1] / 2;

    // Workspace: p[N], r[N], aggdot[N], starts[256], ends[256]  (~1.2 MB)
    float* ws     = (float*)d_ws;
    float* p      = ws;
    float* r      = ws + (size_t)N;
    float* aggdot = ws + 2 * (size_t)N;
    int*   starts = (int*)(ws + 3 * (size_t)N);
    int*   ends   = starts + NGRAPHS;

    k1_dots<<<(N + 3) / 4, 256, 0, stream>>>(x, w_rel, w_root, p, r, aggdot, starts, ends, N);
    int total = E + N;
    k2_scatter<<<(total + 255) / 256, 256, 0, stream>>>(ei, batch, p, aggdot, starts, ends, E, N);
    // scoreg aliases p (dead), wglob aliases aggdot (disjoint phases) — fallback-only
    k4_topk_pool<<<NGRAPHS, 512, 0, stream>>>(x, aggdot, r, b_rel, starts, ends, p, aggdot, out, N);
}

// Round 3
// 162.183 us; speedup vs baseline: 1.3958x; 1.2162x over previous
//
#include <hip/hip_runtime.h>

#define NGRAPHS 256
#define SMAX 4096      // max nodes/graph handled in LDS (actual ~450); global fallback otherwise
#define BIN_RANGE 256  // nodes per bin (dst >> 8)
#define BIN_CAP 6144   // bucket capacity per bin (avg fill 4096, +24 sigma slack)
#define CHUNK 8192     // edges per kA block
#define MAXBINS 512    // LDS histogram capacity (N <= 131072)

// K1: per-node dot products p = x.w_rel, r = x.w_root; zero aggdot/starts/ends;
// init bucket cursors. One wave (64 lanes) per row: lane = feature.
__global__ __launch_bounds__(256) void k1_dots(
    const float* __restrict__ x,
    const float* __restrict__ w_rel,
    const float* __restrict__ w_root,
    float* __restrict__ p, float* __restrict__ r, float* __restrict__ aggdot,
    int* __restrict__ starts, int* __restrict__ ends, int* __restrict__ cursor,
    int N, int NB)
{
    int tid = threadIdx.x;
    if (blockIdx.x == 0) { starts[tid] = 0; ends[tid] = 0; }  // tid in [0,256) == NGRAPHS
    if (blockIdx.x < 2) {
        int b = blockIdx.x * 256 + tid;
        if (b < NB) cursor[b] = b * BIN_CAP;
    }
    int lane = tid & 63;
    int row  = blockIdx.x * 4 + (tid >> 6);
    if (row >= N) return;
    float v = x[(size_t)row * 64 + lane];
    float a = v * w_rel[lane];
    float c = v * w_root[lane];
    #pragma unroll
    for (int off = 32; off > 0; off >>= 1) {
        a += __shfl_down(a, off, 64);
        c += __shfl_down(c, off, 64);
    }
    if (lane == 0) { p[row] = a; r[row] = c; aggdot[row] = 0.0f; }
}

// kA: binned edge scatter. LDS histogram -> one global atomic per (block,bin)
// to reserve bucket space -> non-atomic scatter of (local_dst, p[src]).
__global__ __launch_bounds__(256) void kA_bin(
    const int* __restrict__ ei,      // [2, E]: src then dst
    const float* __restrict__ p,
    uint2* __restrict__ bucket,
    int* cursor,
    int E, int NB)
{
    __shared__ int hist[MAXBINS];
    __shared__ int base[MAXBINS];
    int tid = threadIdx.x;
    for (int b = tid; b < NB; b += 256) hist[b] = 0;
    __syncthreads();
    int beg = blockIdx.x * CHUNK;
    int end = min(beg + CHUNK, E);
    for (int i = beg + tid; i < end; i += 256)
        atomicAdd(&hist[ei[E + i] >> 8], 1);             // LDS atomic
    __syncthreads();
    for (int b = tid; b < NB; b += 256) {
        int c = hist[b];
        base[b] = c ? atomicAdd(&cursor[b], c) : 0;      // global atomic (rare)
        hist[b] = 0;                                     // reuse as local bump cursor
    }
    __syncthreads();
    for (int i = beg + tid; i < end; i += 256) {
        int d = ei[E + i];
        int s = ei[i];
        float v = p[s];
        int b = d >> 8;
        int off = atomicAdd(&hist[b], 1);                // LDS atomic
        int pos = base[b] + off;
        if (pos < (b + 1) * BIN_CAP)                     // overflow guard (never hit)
            bucket[pos] = make_uint2((unsigned)(d & (BIN_RANGE - 1)), __float_as_uint(v));
    }
}

// kB: one block per bin. Segmented reduce of bucket into a 256-float LDS
// accumulator (LDS atomics, CU-local), coalesced write to aggdot.
// Also does graph start/end boundary detection (grid covers all N nodes).
__global__ __launch_bounds__(256) void kB_reduce(
    const uint2* __restrict__ bucket,
    const int* __restrict__ cursor,
    const int* __restrict__ batch,
    float* __restrict__ aggdot,
    int* __restrict__ starts, int* __restrict__ ends,
    int N)
{
    __shared__ float acc[BIN_RANGE];
    int tid = threadIdx.x;
    int b   = blockIdx.x;
    acc[tid] = 0.0f;
    int i = b * 256 + tid;
    if (i < N) {
        int bb = batch[i];
        if (i == 0     || batch[i - 1] != bb) starts[bb] = i;
        if (i == N - 1 || batch[i + 1] != bb) ends[bb]   = i + 1;
    }
    __syncthreads();
    int lo  = b * BIN_CAP;
    int cnt = min(cursor[b], (b + 1) * BIN_CAP) - lo;
    for (int e = tid; e < cnt; e += 256) {
        uint2 ent = bucket[lo + e];
        atomicAdd(&acc[ent.x], __uint_as_float(ent.y));  // LDS float atomic
    }
    __syncthreads();
    int node = b * BIN_RANGE + tid;
    if (node < N) aggdot[node] = acc[tid];
}

// k2 (fallback only, if ws too small for buckets): device-scope atomic scatter.
__global__ __launch_bounds__(256) void k2_scatter(
    const int* __restrict__ ei,
    const int* __restrict__ batch,
    const float* __restrict__ p,
    float* aggdot,
    int* __restrict__ starts, int* __restrict__ ends,
    int E, int N)
{
    int id = blockIdx.x * 256 + threadIdx.x;
    if (id < E) {
        int s = ei[id];
        int d = ei[E + id];
        unsafeAtomicAdd(&aggdot[d], p[s]);
    } else {
        int i = id - E;
        if (i < N) {
            int b = batch[i];
            if (i == 0     || batch[i - 1] != b) starts[b] = i;
            if (i == N - 1 || batch[i + 1] != b) ends[b]   = i + 1;
        }
    }
}

// K4: one block per graph (512 threads).
// Phase 1: score = tanh(aggdot + b + r) into LDS.
// Phase 2: O(n^2) stable rank (matches lexsort tie-break: score desc, index asc).
// Phase 3: branchless float4 weighted pool; rows padded to x32 with zero weights.
__global__ __launch_bounds__(512) void k4_topk_pool(
    const float* __restrict__ x,
    const float* aggdot,             // no restrict: aliased with wglob in fallback
    const float* __restrict__ r,
    const float* __restrict__ brel,
    const int* __restrict__ starts,
    const int* __restrict__ ends,
    float* scoreg,                   // fallback scratch (aliases p; p is dead here)
    float* wglob,                    // fallback scratch (aliases aggdot; disjoint phases)
    float* __restrict__ out, int N)
{
    __shared__ float s[SMAX];
    __shared__ float w[SMAX + 32];
    __shared__ float accs[8][64][4];
    __shared__ int s_cnt;

    int g   = blockIdx.x;
    int tid = threadIdx.x;
    int start = starts[g];
    int n     = ends[g] - start;
    int k     = (n + 1) >> 1;        // ceil(0.5 * n)
    if (tid == 0) s_cnt = 0;
    float b = brel[0];
    bool use_lds = (n <= SMAX);

    if (use_lds) {
        for (int i = tid; i < n; i += 512)
            s[i] = tanhf(aggdot[start + i] + b + r[start + i]);
        __syncthreads();
        int lc = 0;
        for (int i = tid; i < n; i += 512) {
            float si = s[i];
            int rank = 0;
            for (int j = 0; j < n; ++j) {
                float sj = s[j];                 // uniform j: LDS broadcast
                rank += (sj > si) || (sj == si && j < i);
            }
            bool kp = rank < k;
            lc += kp;
            w[i] = kp ? si : 0.0f;
        }
        if (lc) atomicAdd(&s_cnt, lc);
        int n32 = (n + 31) & ~31;
        for (int i = n + tid; i < n32; i += 512) w[i] = 0.0f;
        __syncthreads();

        // Phase 3: wave wg covers rows {wg*4 + 32t + rgrp}; lane = rgrp*16 + fq.
        int wg   = tid >> 6;
        int lane = tid & 63;
        int rgrp = lane >> 4;
        int fq   = lane & 15;
        float a0 = 0.0f, a1 = 0.0f, a2 = 0.0f, a3 = 0.0f;
        #pragma unroll 2
        for (int base = wg * 4; base < n32; base += 32) {
            float wv = w[base + rgrp];
            int row = start + base + rgrp;
            if (row > N - 1) row = N - 1;        // pad rows read safely, weight=0
            const float* xp = x + (size_t)row * 64 + fq * 4;
            float4 v = *(const float4*)xp;
            a0 += v.x * wv; a1 += v.y * wv; a2 += v.z * wv; a3 += v.w * wv;
        }
        accs[wg][lane][0] = a0; accs[wg][lane][1] = a1;
        accs[wg][lane][2] = a2; accs[wg][lane][3] = a3;
        __syncthreads();
        if (tid < 64) {
            int f = tid;
            float sum = 0.0f;
            #pragma unroll
            for (int gg = 0; gg < 8; ++gg)
                #pragma unroll
                for (int rg = 0; rg < 4; ++rg)
                    sum += accs[gg][rg * 16 + (f >> 2)][f & 3];
            out[(size_t)g * 64 + f] = sum / fmaxf((float)s_cnt, 1.0f);
        }
    } else {
        for (int i = tid; i < n; i += 512)
            scoreg[start + i] = tanhf(aggdot[start + i] + b + r[start + i]);
        __syncthreads();
        int lc = 0;
        for (int i = tid; i < n; i += 512) {
            float si = scoreg[start + i];
            int rank = 0;
            for (int j = 0; j < n; ++j) {
                float sj = scoreg[start + j];
                rank += (sj > si) || (sj == si && j < i);
            }
            bool kp = rank < k;
            lc += kp;
            wglob[start + i] = kp ? si : 0.0f;
        }
        if (lc) atomicAdd(&s_cnt, lc);
        __syncthreads();
        int wg   = tid >> 6;
        int lane = tid & 63;
        float acc = 0.0f;
        for (int i = wg; i < n; i += 8) {
            float wv = wglob[start + i];
            acc += x[(size_t)(start + i) * 64 + lane] * wv;
        }
        accs[wg][lane][0] = acc;
        __syncthreads();
        if (tid < 64) {
            float sum = 0.0f;
            #pragma unroll
            for (int gg = 0; gg < 8; ++gg) sum += accs[gg][tid][0];
            out[(size_t)g * 64 + tid] = sum / fmaxf((float)s_cnt, 1.0f);
        }
    }
}

extern "C" void kernel_launch(void* const* d_in, const int* in_sizes, int n_in,
                              void* d_out, int out_size, void* d_ws, size_t ws_size,
                              hipStream_t stream) {
    const float* x      = (const float*)d_in[0];
    const int*   ei     = (const int*)  d_in[1];
    const int*   batch  = (const int*)  d_in[2];
    const float* w_rel  = (const float*)d_in[3];
    const float* b_rel  = (const float*)d_in[4];
    const float* w_root = (const float*)d_in[5];
    float* out = (float*)d_out;

    int N = in_sizes[2];
    int E = in_sizes[1] / 2;
    int NB = (N + BIN_RANGE - 1) / BIN_RANGE;

    // Workspace layout (bytes from d_ws):
    //   p[N], r[N], aggdot[N] floats; starts[256], ends[256], cursor[NB] ints;
    //   bucket[NB * BIN_CAP] uint2 (8-byte aligned).
    char*  wsb    = (char*)d_ws;
    float* p      = (float*)wsb;
    float* r      = p + (size_t)N;
    float* aggdot = p + 2 * (size_t)N;
    int*   starts = (int*)(p + 3 * (size_t)N);
    int*   ends   = starts + NGRAPHS;
    int*   cursor = ends + NGRAPHS;
    size_t bucket_off = (((size_t)(3 * (size_t)N + 2 * NGRAPHS + NB) * 4) + 7) & ~(size_t)7;
    uint2* bucket = (uint2*)(wsb + bucket_off);
    size_t need = bucket_off + (size_t)NB * BIN_CAP * sizeof(uint2);

    bool binned = (need <= ws_size) && (NB <= MAXBINS);

    k1_dots<<<(N + 3) / 4, 256, 0, stream>>>(x, w_rel, w_root, p, r, aggdot,
                                             starts, ends, cursor, N, NB);
    if (binned) {
        int nblkA = (E + CHUNK - 1) / CHUNK;
        kA_bin<<<nblkA, 256, 0, stream>>>(ei, p, bucket, cursor, E, NB);
        kB_reduce<<<NB, 256, 0, stream>>>(bucket, cursor, batch, aggdot, starts, ends, N);
    } else {
        int total = E + N;
        k2_scatter<<<(total + 255) / 256, 256, 0, stream>>>(ei, batch, p, aggdot,
                                                            starts, ends, E, N);
    }
    k4_topk_pool<<<NGRAPHS, 512, 0, stream>>>(x, aggdot, r, b_rel, starts, ends,
                                              p, aggdot, out, N);
}